// Round 1
// baseline (12.462 us; speedup 1.0000x reference)
//
#include <hip/hip_runtime.h>

// Problem constants (from reference):
//   B=32, S=128, V=50257, C=16, F=8
// Inputs (d_in order): logits f32 [B,S,V], mlm_labels int [B,S],
//   labels int [B], weight f32 [C,F], m2c int [C,F], filler_len f32 [C]
// Output: 33 floats = [loss, predictions[0..31]]

#define PB 32
#define PS 128
#define PV 50257
#define PC 16
#define PF 8

__global__ __launch_bounds__(512) void pte_criterion_kernel(
    const float* __restrict__ logits,
    const int*   __restrict__ mlm_labels,
    const int*   __restrict__ labels,
    const float* __restrict__ weight,
    const int*   __restrict__ m2c,
    const float* __restrict__ filler_len,
    float*       __restrict__ out)
{
    __shared__ int   pos_s[PB];
    __shared__ float cls_s[PB][PC];
    __shared__ float loss_s[PB];

    const int tid = threadIdx.x;

    // ---- Phase A: pos[b] = first s with mlm_labels[b,s] >= 0 (argmax of bool) ----
    if (tid < PB) {
        int p = 0;  // jnp.argmax returns 0 if no True
        for (int s = PS - 1; s >= 0; --s) {
            if (mlm_labels[tid * PS + s] >= 0) p = s;
        }
        pos_s[tid] = p;
    }
    __syncthreads();

    // ---- Phase B: cls_logits[b][c] ----
    if (tid < PB * PC) {
        const int b = tid >> 4;
        const int c = tid & 15;
        const float* ml = logits + ((size_t)b * PS + (size_t)pos_s[b]) * (size_t)PV;
        float acc = 0.0f;
        #pragma unroll
        for (int f = 0; f < PF; ++f) {
            const int m = m2c[c * PF + f];
            if (m > 0) {
                acc += ml[m] * weight[c * PF + f];
            }
        }
        cls_s[b][c] = acc / filler_len[c];
    }
    __syncthreads();

    // ---- Phase C: per-row argmax + log_softmax loss ----
    if (tid < PB) {
        const int b = tid;
        float mx = cls_s[b][0];
        int   am = 0;
        #pragma unroll
        for (int c = 1; c < PC; ++c) {
            const float v = cls_s[b][c];
            if (v > mx) { mx = v; am = c; }  // first-max tiebreak, matches jnp.argmax
        }
        float se = 0.0f;
        #pragma unroll
        for (int c = 0; c < PC; ++c) se += expf(cls_s[b][c] - mx);
        const float lse = mx + logf(se);
        loss_s[b] = lse - cls_s[b][labels[b]];
        out[1 + b] = (float)am;  // predictions as float in the flat output
    }
    __syncthreads();

    if (tid == 0) {
        float t = 0.0f;
        #pragma unroll
        for (int b = 0; b < PB; ++b) t += loss_s[b];
        out[0] = t / (float)PB;
    }
}

extern "C" void kernel_launch(void* const* d_in, const int* in_sizes, int n_in,
                              void* d_out, int out_size, void* d_ws, size_t ws_size,
                              hipStream_t stream)
{
    const float* logits     = (const float*)d_in[0];
    const int*   mlm_labels = (const int*)  d_in[1];
    const int*   labels     = (const int*)  d_in[2];
    const float* weight     = (const float*)d_in[3];
    const int*   m2c        = (const int*)  d_in[4];
    const float* filler_len = (const float*)d_in[5];
    float*       out        = (float*)d_out;

    pte_criterion_kernel<<<1, 512, 0, stream>>>(
        logits, mlm_labels, labels, weight, m2c, filler_len, out);
}

// Round 2
// 11.184 us; speedup vs baseline: 1.1143x; 1.1143x over previous
//
#include <hip/hip_runtime.h>

// Problem constants (from reference):
//   B=32, S=128, V=50257, C=16, F=8
// Inputs (d_in order): logits f32 [B,S,V], mlm_labels int [B,S],
//   labels int [B], weight f32 [C,F], m2c int [C,F], filler_len f32 [C]
// Output: 33 floats = [loss, predictions[0..31]]

#define PB 32
#define PS 128
#define PV 50257
#define PC 16
#define PF 8

__global__ __launch_bounds__(512) void pte_criterion_kernel(
    const float* __restrict__ logits,
    const int*   __restrict__ mlm_labels,
    const int*   __restrict__ labels,
    const float* __restrict__ weight,
    const int*   __restrict__ m2c,
    const float* __restrict__ filler_len,
    float*       __restrict__ out)
{
    __shared__ int   pos_s[PB];
    __shared__ int   lab_s[PB];
    __shared__ float fl_s[PC];
    __shared__ int   m2c_s[PC * PF];
    __shared__ float w_s[PC * PF];
    __shared__ float cls_s[PB][PC];
    __shared__ float loss_s[PB];

    const int tid = threadIdx.x;

    // ---- Issue ALL cold loads up front so their HBM misses overlap ----

    // Each thread owns 8 contiguous ints of mlm_labels ([B,S] = 4096 ints,
    // 512 threads x 8). Coalesced int4 loads.
    const int4* ml4 = (const int4*)mlm_labels;
    const int4 v0 = ml4[tid * 2 + 0];
    const int4 v1 = ml4[tid * 2 + 1];

    // Small tables -> LDS, issued by disjoint thread ranges (overlaps with
    // the mlm misses; all drain at the first barrier).
    if (tid < PB) {
        pos_s[tid] = PS;              // sentinel for atomicMin
        lab_s[tid] = labels[tid];
    } else if (tid >= 32 && tid < 32 + PC) {
        fl_s[tid - 32] = filler_len[tid - 32];
    } else if (tid >= 64 && tid < 64 + PC * PF) {
        m2c_s[tid - 64] = m2c[tid - 64];
    } else if (tid >= 192 && tid < 192 + PC * PF) {
        w_s[tid - 192] = weight[tid - 192];
    }
    __syncthreads();

    // ---- Phase A: first s with mlm_labels[b,s] >= 0, via per-chunk scan +
    //      LDS atomicMin. Fully parallel across all 8 waves. ----
    {
        const int b  = tid >> 4;           // 16 threads per row
        const int s0 = (tid & 15) * 8;     // chunk start within the row
        int local = PS;                    // first valid s in this 8-chunk
        // scan backwards so the smallest valid index wins
        if (v1.w >= 0) local = s0 + 7;
        if (v1.z >= 0) local = s0 + 6;
        if (v1.y >= 0) local = s0 + 5;
        if (v1.x >= 0) local = s0 + 4;
        if (v0.w >= 0) local = s0 + 3;
        if (v0.z >= 0) local = s0 + 2;
        if (v0.y >= 0) local = s0 + 1;
        if (v0.x >= 0) local = s0 + 0;
        if (local < PS) atomicMin(&pos_s[b], local);
    }
    __syncthreads();

    // ---- Phase B: cls_logits[b][c] — 4096 scattered f32 gathers ----
    {
        const int b = tid >> 4;
        const int c = tid & 15;
        int p = pos_s[b];
        if (p >= PS) p = 0;                // jnp.argmax fallback (no True)
        const float* ml = logits + ((size_t)b * PS + (size_t)p) * (size_t)PV;
        float acc = 0.0f;
        #pragma unroll
        for (int f = 0; f < PF; ++f) {
            const int m = m2c_s[c * PF + f];
            if (m > 0) {
                acc += ml[m] * w_s[c * PF + f];
            }
        }
        cls_s[b][c] = acc / fl_s[c];
    }
    __syncthreads();

    // ---- Phase C: per-row argmax + log_softmax loss ----
    if (tid < PB) {
        const int b = tid;
        float mx = cls_s[b][0];
        int   am = 0;
        #pragma unroll
        for (int c = 1; c < PC; ++c) {
            const float v = cls_s[b][c];
            if (v > mx) { mx = v; am = c; }   // first-max tiebreak = jnp.argmax
        }
        float se = 0.0f;
        #pragma unroll
        for (int c = 0; c < PC; ++c) se += expf(cls_s[b][c] - mx);
        const float lse = mx + logf(se);
        loss_s[b] = lse - cls_s[b][lab_s[b]];
        out[1 + b] = (float)am;
    }
    __syncthreads();

    if (tid == 0) {
        float t = 0.0f;
        #pragma unroll
        for (int b = 0; b < PB; ++b) t += loss_s[b];
        out[0] = t / (float)PB;
    }
}

extern "C" void kernel_launch(void* const* d_in, const int* in_sizes, int n_in,
                              void* d_out, int out_size, void* d_ws, size_t ws_size,
                              hipStream_t stream)
{
    const float* logits     = (const float*)d_in[0];
    const int*   mlm_labels = (const int*)  d_in[1];
    const int*   labels     = (const int*)  d_in[2];
    const float* weight     = (const float*)d_in[3];
    const int*   m2c        = (const int*)  d_in[4];
    const float* filler_len = (const float*)d_in[5];
    float*       out        = (float*)d_out;

    pte_criterion_kernel<<<1, 512, 0, stream>>>(
        logits, mlm_labels, labels, weight, m2c, filler_len, out);
}

// Round 3
// 9.760 us; speedup vs baseline: 1.2769x; 1.1459x over previous
//
#include <hip/hip_runtime.h>

// Problem constants (from reference):
//   B=32, S=128, V=50257, C=16, F=8
// Inputs (d_in order): logits f32 [B,S,V], mlm_labels int [B,S],
//   labels int [B], weight f32 [C,F], m2c int [C,F], filler_len f32 [C]
// Output: 33 floats = [loss, predictions[0..31]]
//
// Structure: 512 threads = 8 waves; wave w owns rows b = 4w..4w+3 end-to-end
// (16 lanes per row, lane covers class c = lane&15). Zero LDS use except the
// final 32-value loss sum -> exactly ONE __syncthreads on the critical path.

#define PB 32
#define PS 128
#define PV 50257
#define PC 16
#define PF 8

__global__ __launch_bounds__(512) void pte_criterion_kernel(
    const float* __restrict__ logits,
    const int*   __restrict__ mlm_labels,
    const int*   __restrict__ labels,
    const float* __restrict__ weight,
    const int*   __restrict__ m2c,
    const float* __restrict__ filler_len,
    float*       __restrict__ out)
{
    __shared__ float loss_s[PB];

    const int tid  = threadIdx.x;
    const int lane = tid & 63;
    const int g    = lane >> 4;      // 16-lane row-group within the wave
    const int c    = lane & 15;      // class index owned by this lane
    const int b    = tid >> 4;       // row: (tid>>6)*4 + g == tid>>4

    // ---- Issue ALL cold loads up front; every HBM miss overlaps ----
    // mlm_labels chunk: flat ints [8*tid, 8*tid+8) == row b, s in [ (tid&15)*8, +8 )
    const int4* ml4 = (const int4*)mlm_labels;
    const int4 v0 = ml4[tid * 2 + 0];
    const int4 v1 = ml4[tid * 2 + 1];
    // per-lane metadata (redundant across rows; L2/L1 broadcast, still one epoch)
    const int4*   m2c4 = (const int4*)m2c;
    const int4    ma   = m2c4[c * 2 + 0];
    const int4    mb   = m2c4[c * 2 + 1];
    const float4* w4   = (const float4*)weight;
    const float4  wa   = w4[c * 2 + 0];
    const float4  wb   = w4[c * 2 + 1];
    const float   fl   = filler_len[c];
    const int     lab  = labels[b];

    // ---- pos[b]: first s with mlm >= 0, via ballot + shuffle (no LDS) ----
    const int s0 = (tid & 15) * 8;
    int local = PS;
    if (v1.w >= 0) local = s0 + 7;
    if (v1.z >= 0) local = s0 + 6;
    if (v1.y >= 0) local = s0 + 5;
    if (v1.x >= 0) local = s0 + 4;
    if (v0.w >= 0) local = s0 + 3;
    if (v0.z >= 0) local = s0 + 2;
    if (v0.y >= 0) local = s0 + 1;
    if (v0.x >= 0) local = s0 + 0;

    const unsigned long long m  = __ballot(local < PS);
    const unsigned long long gm = (m >> (g * 16)) & 0xFFFFull;
    const int srcLane = g * 16 + (gm ? (__ffsll(gm) - 1) : 0);
    const int pv  = __shfl(local, srcLane, 64);
    const int pos = gm ? pv : 0;     // jnp.argmax fallback when no True

    // ---- cls_logits[b][c]: 8 scattered gathers + FMA (one HBM epoch) ----
    const float* mlrow = logits + ((size_t)b * PS + (size_t)pos) * (size_t)PV;
    float acc = 0.0f;
    if (ma.x > 0) acc += mlrow[ma.x] * wa.x;
    if (ma.y > 0) acc += mlrow[ma.y] * wa.y;
    if (ma.z > 0) acc += mlrow[ma.z] * wa.z;
    if (ma.w > 0) acc += mlrow[ma.w] * wa.w;
    if (mb.x > 0) acc += mlrow[mb.x] * wb.x;
    if (mb.y > 0) acc += mlrow[mb.y] * wb.y;
    if (mb.z > 0) acc += mlrow[mb.z] * wb.z;
    if (mb.w > 0) acc += mlrow[mb.w] * wb.w;
    const float cls = acc / fl;

    // ---- per-row argmax + logsumexp via 16-lane shfl_xor butterflies ----
    float mx = cls;
    int   am = c;
    #pragma unroll
    for (int mask = 1; mask <= 8; mask <<= 1) {
        const float v2 = __shfl_xor(mx, mask, 64);
        const int   i2 = __shfl_xor(am, mask, 64);
        if (v2 > mx || (v2 == mx && i2 < am)) { mx = v2; am = i2; }  // first-max
    }
    float se = expf(cls - mx);
    #pragma unroll
    for (int mask = 1; mask <= 8; mask <<= 1) {
        se += __shfl_xor(se, mask, 64);
    }
    const float clsl = __shfl(cls, g * 16 + lab, 64);
    const float loss = (mx + logf(se)) - clsl;

    if (c == 0) {
        out[1 + b] = (float)am;      // prediction as float
        loss_s[b]  = loss;
    }
    __syncthreads();

    if (tid == 0) {
        float t = 0.0f;
        #pragma unroll
        for (int bb = 0; bb < PB; ++bb) t += loss_s[bb];
        out[0] = t / (float)PB;
    }
}

extern "C" void kernel_launch(void* const* d_in, const int* in_sizes, int n_in,
                              void* d_out, int out_size, void* d_ws, size_t ws_size,
                              hipStream_t stream)
{
    const float* logits     = (const float*)d_in[0];
    const int*   mlm_labels = (const int*)  d_in[1];
    const int*   labels     = (const int*)  d_in[2];
    const float* weight     = (const float*)d_in[3];
    const int*   m2c        = (const int*)  d_in[4];
    const float* filler_len = (const float*)d_in[5];
    float*       out        = (float*)d_out;

    pte_criterion_kernel<<<1, 512, 0, stream>>>(
        logits, mlm_labels, labels, weight, m2c, filler_len, out);
}